// Round 11
// baseline (177.350 us; speedup 1.0000x reference)
//
#include <hip/hip_runtime.h>
#include <hip/hip_bf16.h>

// y[i, d] = x[i, d] * A_diag[d] + B[d]
// N = 262144 rows, D = 512 fp32. HBM-bound streaming FMA.
//
// R11: terminal ladder step — single-wave workgroups. block=64, one
// float4 per thread (1 KB/block), grid 524288. Refill-quantum ladder:
// 16KB/185.5 -> 8KB/182.8 -> 4KB/178.3 -> 2KB/176.4 -> 1KB(1 wave)/?
// A wave is the minimum retire/refill quantum; beyond this only CP
// dispatch rate and WG-slot limits can bind.
//
// Column handling: base = blockIdx*64 + tid covers columns
// (blockIdx*64 + tid) & 127 — even blocks own columns 0..63, odd
// blocks 64..127. j = base & 127 handles both.

typedef float f32x4 __attribute__((ext_vector_type(4)));

#define D4 128                          // 512 / 4 float4 columns

__global__ __launch_bounds__(64) void diag_affine_kernel(
    const f32x4* __restrict__ x,
    const f32x4* __restrict__ A4,
    const f32x4* __restrict__ B4,
    f32x4* __restrict__ out)
{
    const long base = (long)blockIdx.x * 64 + threadIdx.x;
    const int  j    = (int)(base & (D4 - 1));

    const f32x4 a = A4[j];
    const f32x4 b = B4[j];

    f32x4 v = x[base];
    out[base] = v * a + b;
}

extern "C" void kernel_launch(void* const* d_in, const int* in_sizes, int n_in,
                              void* d_out, int out_size, void* d_ws, size_t ws_size,
                              hipStream_t stream) {
    const float* x = (const float*)d_in[0];
    const float* A = (const float*)d_in[1];
    const float* B = (const float*)d_in[2];
    float* out = (float*)d_out;

    const int block = 64;
    const int grid = 524288;   // (262144*512/4) / 64, exact cover

    diag_affine_kernel<<<grid, block, 0, stream>>>(
        reinterpret_cast<const f32x4*>(x),
        reinterpret_cast<const f32x4*>(A),
        reinterpret_cast<const f32x4*>(B),
        reinterpret_cast<f32x4*>(out));
}

// Round 12
// 175.366 us; speedup vs baseline: 1.0113x; 1.0113x over previous
//
#include <hip/hip_runtime.h>
#include <hip/hip_bf16.h>

// y[i, d] = x[i, d] * A_diag[d] + B[d]
// N = 262144 rows, D = 512 fp32. HBM-bound streaming FMA.
//
// FINAL (R10 restored): one-shot, one float4 per thread, block=128
// (2 waves, 2 KB per block), grid 262144. Refill-quantum ladder:
// 16KB/185.5 -> 8KB/182.8 -> 4KB/178.3 -> 2KB/176.4 -> 1KB/177.3 (worse).
// Block=128 is the optimum: 176.4 us = 6.09 TB/s effective = 96.8% of
// the measured mixed-stream copy ceiling (m13: 6.29 TB/s).

typedef float f32x4 __attribute__((ext_vector_type(4)));

#define D4 128                          // 512 / 4 float4 columns

__global__ __launch_bounds__(128) void diag_affine_kernel(
    const f32x4* __restrict__ x,
    const f32x4* __restrict__ A4,
    const f32x4* __restrict__ B4,
    f32x4* __restrict__ out)
{
    // base = blockIdx*128 + tid, so (base & 127) == tid -> fixed column.
    const int j = threadIdx.x;          // 0..127 == float4 column
    const f32x4 a = A4[j];
    const f32x4 b = B4[j];

    const long base = (long)blockIdx.x * 128 + threadIdx.x;

    f32x4 v = x[base];
    out[base] = v * a + b;
}

extern "C" void kernel_launch(void* const* d_in, const int* in_sizes, int n_in,
                              void* d_out, int out_size, void* d_ws, size_t ws_size,
                              hipStream_t stream) {
    const float* x = (const float*)d_in[0];
    const float* A = (const float*)d_in[1];
    const float* B = (const float*)d_in[2];
    float* out = (float*)d_out;

    const int block = 128;
    const int grid = 262144;   // (262144*512/4) / 128 chunks, exact cover

    diag_affine_kernel<<<grid, block, 0, stream>>>(
        reinterpret_cast<const f32x4*>(x),
        reinterpret_cast<const f32x4*>(A),
        reinterpret_cast<const f32x4*>(B),
        reinterpret_cast<f32x4*>(out));
}